// Round 1
// baseline (1569.672 us; speedup 1.0000x reference)
//
#include <hip/hip_runtime.h>
#include <hip/hip_bf16.h>
#include <math.h>

// SelectiveStateSpaceMixer: fp32 correctness-first implementation.
// Pipeline: gemm_in -> conv+silu -> dt/B/C gemm -> parallel scan -> LN ->
//           (y@W_si + D*x)*sigmoid(gate) fused -> gemm_out.
// ws layout (bytes):
//   xz    @ 0          : 8192*4096*4 = 134217728
//   xact  @ 134217728  : 8192*2048*4 =  67108864
//   dtbc  @ 201326592  : 8192* 192*4 =   6291456
//   y     @ 207618048  : 8192*  64*4 =   2097152
//   yn    @ 209715200  : 8192*  64*4 =   2097152   (end: 211812352)

namespace {

constexpr int kInner = 2048;
constexpr int kSeq   = 4096;

__device__ __forceinline__ float sigmoid_f(float x) { return 1.0f / (1.0f + expf(-x)); }

// ---------- generic 128x128x8 fp32 GEMM: C = A@B + bias ----------
__global__ __launch_bounds__(256)
void gemm128(const float* __restrict__ A, const float* __restrict__ B,
             const float* __restrict__ bias, float* __restrict__ C,
             int M, int N, int K)
{
    __shared__ float As[8][128];
    __shared__ float Bs[8][128];
    const int tid  = threadIdx.x;
    const int row0 = blockIdx.y * 128;
    const int col0 = blockIdx.x * 128;
    const int tx = tid & 15, ty = tid >> 4;

    float acc[8][8];
#pragma unroll
    for (int i = 0; i < 8; ++i)
#pragma unroll
        for (int j = 0; j < 8; ++j) acc[i][j] = 0.f;

    const int ai = tid >> 1;          // 0..127  (A tile row)
    const int ak = (tid & 1) * 4;     // 0 or 4  (A tile k)
    const int bk = tid >> 5;          // 0..7    (B tile k)
    const int bj = (tid & 31) * 4;    // 0..124  (B tile col)

    for (int k0 = 0; k0 < K; k0 += 8) {
        float4 av = *reinterpret_cast<const float4*>(A + (size_t)(row0 + ai) * K + k0 + ak);
        float4 bv = *reinterpret_cast<const float4*>(B + (size_t)(k0 + bk) * N + col0 + bj);
        As[ak + 0][ai] = av.x;
        As[ak + 1][ai] = av.y;
        As[ak + 2][ai] = av.z;
        As[ak + 3][ai] = av.w;
        *reinterpret_cast<float4*>(&Bs[bk][bj]) = bv;
        __syncthreads();
#pragma unroll
        for (int kk = 0; kk < 8; ++kk) {
            float4 a0 = *reinterpret_cast<const float4*>(&As[kk][ty * 8]);
            float4 a1 = *reinterpret_cast<const float4*>(&As[kk][ty * 8 + 4]);
            float4 b0 = *reinterpret_cast<const float4*>(&Bs[kk][tx * 8]);
            float4 b1 = *reinterpret_cast<const float4*>(&Bs[kk][tx * 8 + 4]);
            float a[8] = {a0.x, a0.y, a0.z, a0.w, a1.x, a1.y, a1.z, a1.w};
            float b[8] = {b0.x, b0.y, b0.z, b0.w, b1.x, b1.y, b1.z, b1.w};
#pragma unroll
            for (int i = 0; i < 8; ++i)
#pragma unroll
                for (int j = 0; j < 8; ++j)
                    acc[i][j] = fmaf(a[i], b[j], acc[i][j]);
        }
        __syncthreads();
    }

#pragma unroll
    for (int i = 0; i < 8; ++i) {
        float* cp = C + (size_t)(row0 + ty * 8 + i) * N + col0 + tx * 8;
#pragma unroll
        for (int j = 0; j < 8; ++j)
            cp[j] = acc[i][j] + bias[col0 + tx * 8 + j];
    }
}

// ---------- depthwise causal conv (K=3) + bias + SiLU ----------
// out[t] = silu(w0*x[t-2] + w1*x[t-1] + w2*x[t] + cb)
__global__ __launch_bounds__(256)
void conv_silu(const float* __restrict__ xz, const float* __restrict__ cw,
               const float* __restrict__ cb, float* __restrict__ xact)
{
    size_t idx = (size_t)blockIdx.x * 256 + threadIdx.x;  // < 8192*2048
    int    c   = (int)(idx & (kInner - 1));
    size_t r   = idx >> 11;
    int    s   = (int)(r & (kSeq - 1));
    const float* base = xz + r * 4096 + c;   // x_main = first 2048 cols of xz
    float x0 = base[0];
    float x1 = (s >= 1) ? base[-4096] : 0.f;
    float x2 = (s >= 2) ? base[-8192] : 0.f;
    float w0 = cw[c * 3 + 0], w1 = cw[c * 3 + 1], w2 = cw[c * 3 + 2];
    float v  = x2 * w0 + x1 * w1 + x0 * w2 + cb[c];
    xact[idx] = v * sigmoid_f(v);
}

// ---------- dt/B/C projections: X[8192,2048] @ W[2048,64] (z selects W) ----------
__global__ __launch_bounds__(256)
void gemm_dtbc(const float* __restrict__ X,
               const float* __restrict__ Wdt, const float* __restrict__ bdt,
               const float* __restrict__ WB,  const float* __restrict__ bB,
               const float* __restrict__ WC,  const float* __restrict__ bC,
               float* __restrict__ out)  // [8192][192]: dt | B | C
{
    const int z = blockIdx.y;
    const float* W  = (z == 0) ? Wdt : (z == 1) ? WB : WC;
    const float* bb = (z == 0) ? bdt : (z == 1) ? bB : bC;

    __shared__ float As[8][128];
    __shared__ float Bs[8][64];
    const int tid  = threadIdx.x;
    const int row0 = blockIdx.x * 128;
    const int tx = tid & 15, ty = tid >> 4;

    float acc[8][4];
#pragma unroll
    for (int i = 0; i < 8; ++i)
#pragma unroll
        for (int j = 0; j < 4; ++j) acc[i][j] = 0.f;

    const int ai = tid >> 1;
    const int ak = (tid & 1) * 4;
    const int bk = tid >> 5;
    const int bj = (tid & 31) * 2;

    for (int k0 = 0; k0 < kInner; k0 += 8) {
        float4 av = *reinterpret_cast<const float4*>(X + (size_t)(row0 + ai) * kInner + k0 + ak);
        float2 bv = *reinterpret_cast<const float2*>(W + (size_t)(k0 + bk) * 64 + bj);
        As[ak + 0][ai] = av.x;
        As[ak + 1][ai] = av.y;
        As[ak + 2][ai] = av.z;
        As[ak + 3][ai] = av.w;
        *reinterpret_cast<float2*>(&Bs[bk][bj]) = bv;
        __syncthreads();
#pragma unroll
        for (int kk = 0; kk < 8; ++kk) {
            float4 a0 = *reinterpret_cast<const float4*>(&As[kk][ty * 8]);
            float4 a1 = *reinterpret_cast<const float4*>(&As[kk][ty * 8 + 4]);
            float4 b  = *reinterpret_cast<const float4*>(&Bs[kk][tx * 4]);
            float a[8] = {a0.x, a0.y, a0.z, a0.w, a1.x, a1.y, a1.z, a1.w};
            float bf[4] = {b.x, b.y, b.z, b.w};
#pragma unroll
            for (int i = 0; i < 8; ++i)
#pragma unroll
                for (int j = 0; j < 4; ++j)
                    acc[i][j] = fmaf(a[i], bf[j], acc[i][j]);
        }
        __syncthreads();
    }

#pragma unroll
    for (int i = 0; i < 8; ++i) {
        size_t r = (size_t)(row0 + ty * 8 + i);
#pragma unroll
        for (int j = 0; j < 4; ++j) {
            int   c = tx * 4 + j;
            float v = acc[i][j] + bb[c];
            if (z == 0) v = sigmoid_f(v);   // dt = sigmoid(...)
            out[r * 192 + z * 64 + c] = v;
        }
    }
}

// ---------- selective scan: s_t = (1-dt)*s + dt*B ; y = C*s ----------
// one block per (batch, state-channel); affine-transform Hillis-Steele scan
__global__ __launch_bounds__(256)
void scan_kernel(const float* __restrict__ dtbc, float* __restrict__ y)
{
    const int b = blockIdx.x >> 6;
    const int d = blockIdx.x & 63;
    const int t = threadIdx.x;
    const int s0 = t * 16;
    const size_t rbase = (size_t)b * kSeq;

    float av[16], bv[16];
    float Acc = 1.f, Bcc = 0.f;
#pragma unroll
    for (int i = 0; i < 16; ++i) {
        size_t r  = rbase + s0 + i;
        float  dt = dtbc[r * 192 + d];
        float  Bv = dtbc[r * 192 + 64 + d];
        float  a  = 1.f - dt;
        float  bb = dt * Bv;
        av[i] = a; bv[i] = bb;
        Acc = a * Acc;
        Bcc = a * Bcc + bb;
    }

    __shared__ float sA[256], sB[256];
    sA[t] = Acc; sB[t] = Bcc;
    __syncthreads();
    for (int off = 1; off < 256; off <<= 1) {
        float cA = sA[t], cB = sB[t];
        float pA = 1.f, pB = 0.f;
        if (t >= off) { pA = sA[t - off]; pB = sB[t - off]; }
        __syncthreads();
        if (t >= off) { sA[t] = cA * pA; sB[t] = cA * pB + cB; }
        __syncthreads();
    }

    float s = (t == 0) ? 0.f : sB[t - 1];   // state entering this chunk (s_init = 0)
#pragma unroll
    for (int i = 0; i < 16; ++i) {
        size_t r = rbase + s0 + i;
        s = av[i] * s + bv[i];
        float C = dtbc[r * 192 + 128 + d];
        y[r * 64 + d] = C * s;
    }
}

// ---------- LayerNorm over 64 states (no affine) ----------
__global__ __launch_bounds__(256)
void ln_kernel(const float* __restrict__ y, float* __restrict__ yn)
{
    const int w = threadIdx.x >> 6;
    const int l = threadIdx.x & 63;
    const size_t r = (size_t)blockIdx.x * 4 + w;
    float v  = y[r * 64 + l];
    float s  = v, s2 = v * v;
#pragma unroll
    for (int m = 1; m < 64; m <<= 1) {
        s  += __shfl_xor(s, m, 64);
        s2 += __shfl_xor(s2, m, 64);
    }
    float mu  = s * (1.f / 64.f);
    float var = s2 * (1.f / 64.f) - mu * mu;
    yn[r * 64 + l] = (v - mu) * rsqrtf(var + 1e-5f);
}

// ---------- h = (yn@W_si + b_si + D*xact) * sigmoid(gate), in-place over xact ----------
__global__ __launch_bounds__(256)
void mix_kernel(const float* __restrict__ yn,    // [8192][64]
                const float* __restrict__ Wsi,   // [64][2048]
                const float* __restrict__ bsi,
                const float* __restrict__ Dv,
                const float* __restrict__ xz,    // gate = xz[:, 2048+c]
                float* __restrict__ xact)        // in-out [8192][2048]
{
    __shared__ float Ys[64][64];     // [k][row]
    __shared__ float Ws[64][128];    // [k][col]
    const int tid = threadIdx.x;
    const int r0  = blockIdx.y * 64;
    const int c0  = blockIdx.x * 128;

    {   // load Y tile (transpose to [k][row])
        int row = tid >> 2;
        int k0  = (tid & 3) * 16;
#pragma unroll
        for (int i = 0; i < 4; ++i) {
            float4 v = *reinterpret_cast<const float4*>(yn + (size_t)(r0 + row) * 64 + k0 + i * 4);
            Ys[k0 + i * 4 + 0][row] = v.x;
            Ys[k0 + i * 4 + 1][row] = v.y;
            Ys[k0 + i * 4 + 2][row] = v.z;
            Ys[k0 + i * 4 + 3][row] = v.w;
        }
    }
    {   // load W_si tile
        int k  = tid >> 2;
        int j0 = (tid & 3) * 32;
#pragma unroll
        for (int i = 0; i < 8; ++i) {
            float4 v = *reinterpret_cast<const float4*>(Wsi + (size_t)k * kInner + c0 + j0 + i * 4);
            *reinterpret_cast<float4*>(&Ws[k][j0 + i * 4]) = v;
        }
    }
    __syncthreads();

    const int tx = tid & 31, ty = tid >> 5;   // 8 rows x 4 cols per thread
    float acc[8][4];
#pragma unroll
    for (int i = 0; i < 8; ++i)
#pragma unroll
        for (int j = 0; j < 4; ++j) acc[i][j] = 0.f;

#pragma unroll 4
    for (int k = 0; k < 64; ++k) {
        float4 a0 = *reinterpret_cast<const float4*>(&Ys[k][ty * 8]);
        float4 a1 = *reinterpret_cast<const float4*>(&Ys[k][ty * 8 + 4]);
        float4 b  = *reinterpret_cast<const float4*>(&Ws[k][tx * 4]);
        float a[8]  = {a0.x, a0.y, a0.z, a0.w, a1.x, a1.y, a1.z, a1.w};
        float bf[4] = {b.x, b.y, b.z, b.w};
#pragma unroll
        for (int i = 0; i < 8; ++i)
#pragma unroll
            for (int j = 0; j < 4; ++j)
                acc[i][j] = fmaf(a[i], bf[j], acc[i][j]);
    }

#pragma unroll
    for (int i = 0; i < 8; ++i) {
        size_t r = (size_t)(r0 + ty * 8 + i);
#pragma unroll
        for (int j = 0; j < 4; ++j) {
            int   c  = c0 + tx * 4 + j;
            float g  = xz[r * 4096 + 2048 + c];
            float xa = xact[r * 2048 + c];
            float v  = acc[i][j] + bsi[c] + Dv[c] * xa;
            xact[r * 2048 + c] = v * sigmoid_f(g);
        }
    }
}

}  // namespace

extern "C" void kernel_launch(void* const* d_in, const int* in_sizes, int n_in,
                              void* d_out, int out_size, void* d_ws, size_t ws_size,
                              hipStream_t stream)
{
    (void)in_sizes; (void)n_in; (void)out_size; (void)ws_size;
    const float* x     = (const float*)d_in[0];
    const float* W_in  = (const float*)d_in[1];
    const float* b_in  = (const float*)d_in[2];
    const float* cw    = (const float*)d_in[3];
    const float* cb    = (const float*)d_in[4];
    const float* W_dt  = (const float*)d_in[5];
    const float* b_dt  = (const float*)d_in[6];
    const float* W_B   = (const float*)d_in[7];
    const float* b_B   = (const float*)d_in[8];
    const float* W_C   = (const float*)d_in[9];
    const float* b_C   = (const float*)d_in[10];
    const float* W_si  = (const float*)d_in[11];
    const float* b_si  = (const float*)d_in[12];
    const float* Dv    = (const float*)d_in[13];
    const float* W_out = (const float*)d_in[14];
    const float* b_out = (const float*)d_in[15];
    float* out = (float*)d_out;

    char*  ws    = (char*)d_ws;
    float* xz    = (float*)(ws);
    float* xact  = (float*)(ws + 134217728);
    float* dtbc  = (float*)(ws + 201326592);
    float* ybuf  = (float*)(ws + 207618048);
    float* ynbuf = (float*)(ws + 209715200);

    dim3 blk(256);
    // xz = x @ W_in + b_in                        [8192,4096]
    gemm128<<<dim3(4096 / 128, 8192 / 128), blk, 0, stream>>>(x, W_in, b_in, xz, 8192, 4096, 1024);
    // xact = silu(causal_conv(xz[:, :2048]))      [8192,2048]
    conv_silu<<<dim3((8192 * 2048) / 256), blk, 0, stream>>>(xz, cw, cb, xact);
    // dtbc = [sigmoid(xact@W_dt+b), xact@W_B+b, xact@W_C+b]   [8192,192]
    gemm_dtbc<<<dim3(8192 / 128, 3), blk, 0, stream>>>(xact, W_dt, b_dt, W_B, b_B, W_C, b_C, dtbc);
    // y = selective_scan(dt, B, C)                [8192,64]
    scan_kernel<<<dim3(128), blk, 0, stream>>>(dtbc, ybuf);
    // yn = layernorm(y)
    ln_kernel<<<dim3(8192 / 4), blk, 0, stream>>>(ybuf, ynbuf);
    // xact = (yn@W_si + b_si + D*xact) * sigmoid(gate)   (in place)
    mix_kernel<<<dim3(2048 / 128, 8192 / 64), blk, 0, stream>>>(ynbuf, W_si, b_si, Dv, xz, xact);
    // out = xact @ W_out + b_out                  [8192,1024]
    gemm128<<<dim3(1024 / 128, 8192 / 128), blk, 0, stream>>>(xact, W_out, b_out, out, 8192, 1024, 2048);
}

// Round 2
// 320.654 us; speedup vs baseline: 4.8952x; 4.8952x over previous
//
#include <hip/hip_runtime.h>
#include <hip/hip_bf16.h>
#include <math.h>

// SelectiveStateSpaceMixer — round 2: bf16 MFMA GEMMs (16x16x32), fp32 elsewhere.
// ws layout (bytes):
//   xmain  f32 [8192][2048]  67108864 @ 0
//   gateb  bf16[8192][2048]  33554432 @ 67108864
//   xb     bf16[8192][1024]  16777216 @ 100663296
//   xact   bf16[8192][2048]  33554432 @ 117440512
//   hb     bf16[8192][2048]  33554432 @ 150994944
//   dtbc   f32 [8192][192]    6291456 @ 184549376
//   ybuf   f32 [8192][64]     2097152 @ 190840832
//   ynbuf  f32 [8192][64]     2097152 @ 192937984
//   WinT   bf16[4096][1024]   8388608 @ 195035136
//   WoutT  bf16[1024][2048]   4194304 @ 203423744
//   WdtbcT bf16[192][2048]     786432 @ 207618048   end 208404480

namespace {

typedef __bf16 bf16x8 __attribute__((ext_vector_type(8)));
typedef float  f32x4  __attribute__((ext_vector_type(4)));
typedef unsigned short u16;

constexpr int kInner = 2048;
constexpr int kSeq   = 4096;

__device__ __forceinline__ float sigmoid_f(float x) { return 1.0f / (1.0f + expf(-x)); }
__device__ __forceinline__ u16   f2bf(float f) { __bf16 h = (__bf16)f; return __builtin_bit_cast(u16, h); }
__device__ __forceinline__ float bf2f(u16 u)   { return (float)__builtin_bit_cast(__bf16, u); }

// ---------- fp32 -> bf16 elementwise (n multiple of 4) ----------
__global__ __launch_bounds__(256)
void convert_bf16(const float* __restrict__ in, u16* __restrict__ out, long n4)
{
    long i = (long)blockIdx.x * 256 + threadIdx.x;
    if (i >= n4) return;
    float4 v = reinterpret_cast<const float4*>(in)[i];
    ushort4 o = make_ushort4(f2bf(v.x), f2bf(v.y), f2bf(v.z), f2bf(v.w));
    reinterpret_cast<ushort4*>(out)[i] = o;
}

// ---------- fp32 [R][C] -> bf16 [C][R] (R,C multiples of 32) ----------
__global__ __launch_bounds__(256)
void transpose_bf16(const float* __restrict__ in, u16* __restrict__ out, int R, int C)
{
    __shared__ float tile[32][33];
    const int r0 = blockIdx.y * 32, c0 = blockIdx.x * 32;
    const int t  = threadIdx.x;
    const int lr = t >> 3, lc = (t & 7) * 4;
    float4 v = *reinterpret_cast<const float4*>(in + (size_t)(r0 + lr) * C + c0 + lc);
    tile[lr][lc + 0] = v.x; tile[lr][lc + 1] = v.y;
    tile[lr][lc + 2] = v.z; tile[lr][lc + 3] = v.w;
    __syncthreads();
    const int oc = t >> 3, orr = (t & 7) * 4;
    ushort4 o = make_ushort4(f2bf(tile[orr + 0][oc]), f2bf(tile[orr + 1][oc]),
                             f2bf(tile[orr + 2][oc]), f2bf(tile[orr + 3][oc]));
    *reinterpret_cast<ushort4*>(out + (size_t)(c0 + oc) * R + r0 + orr) = o;
}

// ---------- bf16 MFMA GEMM: C[M][N] = A[M][K] @ Bt[N][K]^T + bias ----------
// 4 waves (2x2), wave tile (BM/2)x(BN/2), 16x16x32 MFMA, LDS pad 32->40.
// EPI 0: fp32 out, ldc=N, bias b0
// EPI 1: gemm_in split: col<2048 -> fp32 o0 (ldc 2048); col>=2048 -> bf16 o1 (gate)
// EPI 2: dtbc: fp32 out ldc=192; bias b0|b1|b2 per 64-col group; sigmoid on col<64
template <int BM, int BN, int EPI>
__global__ __launch_bounds__(256)
void gemm_mfma(const u16* __restrict__ A, const u16* __restrict__ Bt,
               const float* __restrict__ b0, const float* __restrict__ b1,
               const float* __restrict__ b2,
               void* __restrict__ o0, void* __restrict__ o1,
               int M, int N, int K)
{
    constexpr int FM = BM / 32, FN = BN / 32;
    constexpr int RA = (BM * 4) / 256, RB = (BN * 4) / 256;
    __shared__ __align__(16) u16 As[BM][40];
    __shared__ __align__(16) u16 Bs[BN][40];

    const int tid  = threadIdx.x;
    const int lane = tid & 63;
    const int wid  = tid >> 6;
    const int wr   = (wid >> 1) * (BM / 2);
    const int wc   = (wid & 1)  * (BN / 2);
    const int row0 = blockIdx.y * BM;
    const int col0 = blockIdx.x * BN;

    f32x4 acc[FM][FN];
#pragma unroll
    for (int m = 0; m < FM; ++m)
#pragma unroll
        for (int n = 0; n < FN; ++n) acc[m][n] = (f32x4){0.f, 0.f, 0.f, 0.f};

    const int sr = tid >> 2;        // staging row (0..63)
    const int sc = (tid & 3) * 8;   // staging col (bf16 units)
    const int fr = lane & 15;
    const int fq = lane >> 4;
    const int kb = fq * 8;

    for (int k0 = 0; k0 < K; k0 += 32) {
#pragma unroll
        for (int i = 0; i < RA; ++i) {
            int r = i * 64 + sr;
            *reinterpret_cast<uint4*>(&As[r][sc]) =
                *reinterpret_cast<const uint4*>(A + (size_t)(row0 + r) * K + k0 + sc);
        }
#pragma unroll
        for (int i = 0; i < RB; ++i) {
            int r = i * 64 + sr;
            *reinterpret_cast<uint4*>(&Bs[r][sc]) =
                *reinterpret_cast<const uint4*>(Bt + (size_t)(col0 + r) * K + k0 + sc);
        }
        __syncthreads();
        bf16x8 af[FM], bg[FN];
#pragma unroll
        for (int m = 0; m < FM; ++m)
            af[m] = *reinterpret_cast<const bf16x8*>(&As[wr + m * 16 + fr][kb]);
#pragma unroll
        for (int n = 0; n < FN; ++n)
            bg[n] = *reinterpret_cast<const bf16x8*>(&Bs[wc + n * 16 + fr][kb]);
#pragma unroll
        for (int m = 0; m < FM; ++m)
#pragma unroll
            for (int n = 0; n < FN; ++n)
                acc[m][n] = __builtin_amdgcn_mfma_f32_16x16x32_bf16(af[m], bg[n], acc[m][n], 0, 0, 0);
        __syncthreads();
    }

#pragma unroll
    for (int m = 0; m < FM; ++m) {
#pragma unroll
        for (int n = 0; n < FN; ++n) {
            const int gc = col0 + wc + n * 16 + fr;
#pragma unroll
            for (int j = 0; j < 4; ++j) {
                const int gr = row0 + wr + m * 16 + fq * 4 + j;
                float v = acc[m][n][j];
                if constexpr (EPI == 0) {
                    v += b0[gc];
                    ((float*)o0)[(size_t)gr * N + gc] = v;
                } else if constexpr (EPI == 1) {
                    v += b0[gc];
                    if (gc < 2048) ((float*)o0)[(size_t)gr * 2048 + gc] = v;
                    else           ((u16*)o1)[(size_t)gr * 2048 + gc - 2048] = f2bf(v);
                } else {
                    float bb = (gc < 64) ? b0[gc] : (gc < 128) ? b1[gc - 64] : b2[gc - 128];
                    v += bb;
                    if (gc < 64) v = sigmoid_f(v);
                    ((float*)o0)[(size_t)gr * 192 + gc] = v;
                }
            }
        }
    }
    (void)b1; (void)b2; (void)o1; (void)M;
}

// ---------- depthwise causal conv (K=3) + bias + SiLU -> bf16 ----------
__global__ __launch_bounds__(256)
void conv_silu(const float* __restrict__ xmain, const float* __restrict__ cw,
               const float* __restrict__ cb, u16* __restrict__ xact)
{
    size_t idx = (size_t)blockIdx.x * 256 + threadIdx.x;  // < 8192*2048
    int    c   = (int)(idx & (kInner - 1));
    size_t r   = idx >> 11;
    int    s   = (int)(r & (kSeq - 1));
    const float* base = xmain + idx;
    float x0 = base[0];
    float x1 = (s >= 1) ? base[-2048] : 0.f;
    float x2 = (s >= 2) ? base[-4096] : 0.f;
    float v  = x2 * cw[c * 3 + 0] + x1 * cw[c * 3 + 1] + x0 * cw[c * 3 + 2] + cb[c];
    xact[idx] = f2bf(v * sigmoid_f(v));
}

// ---------- selective scan: s_t = (1-dt)*s + dt*B ; y = C*s ----------
__global__ __launch_bounds__(256)
void scan_kernel(const float* __restrict__ dtbc, float* __restrict__ y)
{
    const int b = blockIdx.x >> 6;
    const int d = blockIdx.x & 63;
    const int t = threadIdx.x;
    const int s0 = t * 16;
    const size_t rbase = (size_t)b * kSeq;

    float av[16], bv[16];
    float Acc = 1.f, Bcc = 0.f;
#pragma unroll
    for (int i = 0; i < 16; ++i) {
        size_t r  = rbase + s0 + i;
        float  dt = dtbc[r * 192 + d];
        float  Bv = dtbc[r * 192 + 64 + d];
        float  a  = 1.f - dt;
        float  bb = dt * Bv;
        av[i] = a; bv[i] = bb;
        Acc = a * Acc;
        Bcc = a * Bcc + bb;
    }

    __shared__ float sA[256], sB[256];
    sA[t] = Acc; sB[t] = Bcc;
    __syncthreads();
    for (int off = 1; off < 256; off <<= 1) {
        float cA = sA[t], cB = sB[t];
        float pA = 1.f, pB = 0.f;
        if (t >= off) { pA = sA[t - off]; pB = sB[t - off]; }
        __syncthreads();
        if (t >= off) { sA[t] = cA * pA; sB[t] = cA * pB + cB; }
        __syncthreads();
    }

    float s = (t == 0) ? 0.f : sB[t - 1];
#pragma unroll
    for (int i = 0; i < 16; ++i) {
        size_t r = rbase + s0 + i;
        s = av[i] * s + bv[i];
        y[r * 64 + d] = dtbc[r * 192 + 128 + d] * s;
    }
}

// ---------- LayerNorm over 64 states ----------
__global__ __launch_bounds__(256)
void ln_kernel(const float* __restrict__ y, float* __restrict__ yn)
{
    const int w = threadIdx.x >> 6;
    const int l = threadIdx.x & 63;
    const size_t r = (size_t)blockIdx.x * 4 + w;
    float v  = y[r * 64 + l];
    float s  = v, s2 = v * v;
#pragma unroll
    for (int m = 1; m < 64; m <<= 1) {
        s  += __shfl_xor(s, m, 64);
        s2 += __shfl_xor(s2, m, 64);
    }
    float mu  = s * (1.f / 64.f);
    float var = s2 * (1.f / 64.f) - mu * mu;
    yn[r * 64 + l] = (v - mu) * rsqrtf(var + 1e-5f);
}

// ---------- h = (yn@W_si + b_si + D*xact) * sigmoid(gate) -> bf16 ----------
__global__ __launch_bounds__(256)
void mix_kernel(const float* __restrict__ yn,    // [8192][64]
                const float* __restrict__ Wsi,   // [64][2048]
                const float* __restrict__ bsi,
                const float* __restrict__ Dv,
                const u16*   __restrict__ gateb, // [8192][2048] bf16
                const u16*   __restrict__ xact,  // [8192][2048] bf16
                u16*         __restrict__ hb)    // [8192][2048] bf16
{
    __shared__ float Ys[64][64];     // [k][row]
    __shared__ float Ws[64][128];    // [k][col]
    const int tid = threadIdx.x;
    const int r0  = blockIdx.y * 64;
    const int c0  = blockIdx.x * 128;

    {
        int row = tid >> 2;
        int k0  = (tid & 3) * 16;
#pragma unroll
        for (int i = 0; i < 4; ++i) {
            float4 v = *reinterpret_cast<const float4*>(yn + (size_t)(r0 + row) * 64 + k0 + i * 4);
            Ys[k0 + i * 4 + 0][row] = v.x;
            Ys[k0 + i * 4 + 1][row] = v.y;
            Ys[k0 + i * 4 + 2][row] = v.z;
            Ys[k0 + i * 4 + 3][row] = v.w;
        }
    }
    {
        int k  = tid >> 2;
        int j0 = (tid & 3) * 32;
#pragma unroll
        for (int i = 0; i < 8; ++i) {
            float4 v = *reinterpret_cast<const float4*>(Wsi + (size_t)k * kInner + c0 + j0 + i * 4);
            *reinterpret_cast<float4*>(&Ws[k][j0 + i * 4]) = v;
        }
    }
    __syncthreads();

    const int tx = tid & 31, ty = tid >> 5;
    float acc[8][4];
#pragma unroll
    for (int i = 0; i < 8; ++i)
#pragma unroll
        for (int j = 0; j < 4; ++j) acc[i][j] = 0.f;

#pragma unroll 4
    for (int k = 0; k < 64; ++k) {
        float4 a0 = *reinterpret_cast<const float4*>(&Ys[k][ty * 8]);
        float4 a1 = *reinterpret_cast<const float4*>(&Ys[k][ty * 8 + 4]);
        float4 b  = *reinterpret_cast<const float4*>(&Ws[k][tx * 4]);
        float a[8]  = {a0.x, a0.y, a0.z, a0.w, a1.x, a1.y, a1.z, a1.w};
        float bf[4] = {b.x, b.y, b.z, b.w};
#pragma unroll
        for (int i = 0; i < 8; ++i)
#pragma unroll
            for (int j = 0; j < 4; ++j)
                acc[i][j] = fmaf(a[i], bf[j], acc[i][j]);
    }

#pragma unroll
    for (int i = 0; i < 8; ++i) {
        size_t r = (size_t)(r0 + ty * 8 + i);
        size_t p = r * kInner + c0 + tx * 4;
        ushort4 gv = *reinterpret_cast<const ushort4*>(&gateb[p]);
        ushort4 xv = *reinterpret_cast<const ushort4*>(&xact[p]);
        float g[4]  = {bf2f(gv.x), bf2f(gv.y), bf2f(gv.z), bf2f(gv.w)};
        float xa[4] = {bf2f(xv.x), bf2f(xv.y), bf2f(xv.z), bf2f(xv.w)};
        ushort4 o;
        u16* op = reinterpret_cast<u16*>(&o);
#pragma unroll
        for (int j = 0; j < 4; ++j) {
            int   c = c0 + tx * 4 + j;
            float v = acc[i][j] + bsi[c] + Dv[c] * xa[j];
            op[j] = f2bf(v * sigmoid_f(g[j]));
        }
        *reinterpret_cast<ushort4*>(&hb[p]) = o;
    }
}

}  // namespace

extern "C" void kernel_launch(void* const* d_in, const int* in_sizes, int n_in,
                              void* d_out, int out_size, void* d_ws, size_t ws_size,
                              hipStream_t stream)
{
    (void)in_sizes; (void)n_in; (void)out_size; (void)ws_size;
    const float* x     = (const float*)d_in[0];
    const float* W_in  = (const float*)d_in[1];
    const float* b_in  = (const float*)d_in[2];
    const float* cw    = (const float*)d_in[3];
    const float* cb    = (const float*)d_in[4];
    const float* W_dt  = (const float*)d_in[5];
    const float* b_dt  = (const float*)d_in[6];
    const float* W_B   = (const float*)d_in[7];
    const float* b_B   = (const float*)d_in[8];
    const float* W_C   = (const float*)d_in[9];
    const float* b_C   = (const float*)d_in[10];
    const float* W_si  = (const float*)d_in[11];
    const float* b_si  = (const float*)d_in[12];
    const float* Dv    = (const float*)d_in[13];
    const float* W_out = (const float*)d_in[14];
    const float* b_out = (const float*)d_in[15];
    float* out = (float*)d_out;

    char* ws = (char*)d_ws;
    float* xmain  = (float*)(ws);
    u16*   gateb  = (u16*)  (ws + 67108864);
    u16*   xb     = (u16*)  (ws + 100663296);
    u16*   xact   = (u16*)  (ws + 117440512);
    u16*   hb     = (u16*)  (ws + 150994944);
    float* dtbc   = (float*)(ws + 184549376);
    float* ybuf   = (float*)(ws + 190840832);
    float* ynbuf  = (float*)(ws + 192937984);
    u16*   WinT   = (u16*)  (ws + 195035136);
    u16*   WoutT  = (u16*)  (ws + 203423744);
    u16*   WdtbcT = (u16*)  (ws + 207618048);

    dim3 blk(256);

    // weight/activation conversions
    convert_bf16<<<dim3((8192L * 1024 / 4 + 255) / 256), blk, 0, stream>>>(x, xb, 8192L * 1024 / 4);
    transpose_bf16<<<dim3(4096 / 32, 1024 / 32), blk, 0, stream>>>(W_in,  WinT,  1024, 4096);
    transpose_bf16<<<dim3(1024 / 32, 2048 / 32), blk, 0, stream>>>(W_out, WoutT, 2048, 1024);
    transpose_bf16<<<dim3(64 / 32, 2048 / 32), blk, 0, stream>>>(W_dt, WdtbcT,            2048, 64);
    transpose_bf16<<<dim3(64 / 32, 2048 / 32), blk, 0, stream>>>(W_B,  WdtbcT +  64 * 2048, 2048, 64);
    transpose_bf16<<<dim3(64 / 32, 2048 / 32), blk, 0, stream>>>(W_C,  WdtbcT + 128 * 2048, 2048, 64);

    // xz = x @ W_in + b_in  (split: xmain fp32 | gate bf16)
    gemm_mfma<128, 128, 1><<<dim3(4096 / 128, 8192 / 128), blk, 0, stream>>>(
        xb, WinT, b_in, nullptr, nullptr, xmain, gateb, 8192, 4096, 1024);
    // xact = silu(causal_conv(xmain))
    conv_silu<<<dim3((8192 * 2048) / 256), blk, 0, stream>>>(xmain, cw, cb, xact);
    // dtbc = [sigmoid(xact@W_dt+b), xact@W_B+b, xact@W_C+b]
    gemm_mfma<64, 64, 2><<<dim3(192 / 64, 8192 / 64), blk, 0, stream>>>(
        xact, WdtbcT, b_dt, b_B, b_C, dtbc, nullptr, 8192, 192, 2048);
    // y = selective_scan(dt, B, C)
    scan_kernel<<<dim3(128), blk, 0, stream>>>(dtbc, ybuf);
    // yn = layernorm(y)
    ln_kernel<<<dim3(8192 / 4), blk, 0, stream>>>(ybuf, ynbuf);
    // hb = (yn@W_si + b_si + D*xact) * sigmoid(gate)
    mix_kernel<<<dim3(2048 / 128, 8192 / 64), blk, 0, stream>>>(
        ynbuf, W_si, b_si, Dv, gateb, xact, hb);
    // out = hb @ W_out + b_out
    gemm_mfma<128, 128, 0><<<dim3(1024 / 128, 8192 / 128), blk, 0, stream>>>(
        hb, WoutT, b_out, nullptr, nullptr, out, nullptr, 8192, 1024, 2048);
}

// Round 3
// 271.556 us; speedup vs baseline: 5.7803x; 1.1808x over previous
//
#include <hip/hip_runtime.h>
#include <hip/hip_bf16.h>
#include <math.h>

// SelectiveStateSpaceMixer — round 3: global_load_lds GEMMs (m97 structure),
// transposed dtbc for coalesced scan, MFMA mix, all-bf16 activations.
// ws layout (bytes):
//   xzb    bf16[8192][4096]  67108864 @ 0
//   xb     bf16[8192][1024]  16777216 @ 67108864
//   xact   bf16[8192][2048]  33554432 @ 83886080
//   hb     bf16[8192][2048]  33554432 @ 117440512
//   dtbcT  f32 [192][8192]    6291456 @ 150994944
//   ybuf   f32 [8192][64]     2097152 @ 157286400
//   ynb    bf16[8192][64]     1048576 @ 159383552
//   WinT   bf16[4096][1024]   8388608 @ 160432128
//   WoutT  bf16[1024][2048]   4194304 @ 168820736
//   WdtbcT bf16[192][2048]     786432 @ 173015040
//   WsiT   bf16[2048][64]      262144 @ 173801472   end 174063616

namespace {

typedef __bf16 bf16x8 __attribute__((ext_vector_type(8)));
typedef float  f32x4  __attribute__((ext_vector_type(4)));
typedef unsigned short u16;

constexpr int kSeq = 4096;

__device__ __forceinline__ float sigmoid_f(float x) { return 1.0f / (1.0f + expf(-x)); }
__device__ __forceinline__ u16   f2bf(float f) { __bf16 h = (__bf16)f; return __builtin_bit_cast(u16, h); }
__device__ __forceinline__ float bf2f(u16 u)   { return (float)__builtin_bit_cast(__bf16, u); }

// async global->LDS, 16B per lane
__device__ __forceinline__ void gll16(const u16* g, u16* l) {
    __builtin_amdgcn_global_load_lds(
        (const __attribute__((address_space(1))) unsigned int*)g,
        (__attribute__((address_space(3))) unsigned int*)l,
        16, 0, 0);
}

// ---------- fp32 -> bf16 elementwise ----------
__global__ __launch_bounds__(256)
void convert_bf16(const float* __restrict__ in, u16* __restrict__ out, long n4)
{
    long i = (long)blockIdx.x * 256 + threadIdx.x;
    if (i >= n4) return;
    float4 v = reinterpret_cast<const float4*>(in)[i];
    ushort4 o = make_ushort4(f2bf(v.x), f2bf(v.y), f2bf(v.z), f2bf(v.w));
    reinterpret_cast<ushort4*>(out)[i] = o;
}

// ---------- fp32 [R][C] -> bf16 [C][R] ----------
__global__ __launch_bounds__(256)
void transpose_bf16(const float* __restrict__ in, u16* __restrict__ out, int R, int C)
{
    __shared__ float tile[32][33];
    const int r0 = blockIdx.y * 32, c0 = blockIdx.x * 32;
    const int t  = threadIdx.x;
    const int lr = t >> 3, lc = (t & 7) * 4;
    float4 v = *reinterpret_cast<const float4*>(in + (size_t)(r0 + lr) * C + c0 + lc);
    tile[lr][lc + 0] = v.x; tile[lr][lc + 1] = v.y;
    tile[lr][lc + 2] = v.z; tile[lr][lc + 3] = v.w;
    __syncthreads();
    const int oc = t >> 3, orr = (t & 7) * 4;
    ushort4 o = make_ushort4(f2bf(tile[orr + 0][oc]), f2bf(tile[orr + 1][oc]),
                             f2bf(tile[orr + 2][oc]), f2bf(tile[orr + 3][oc]));
    *reinterpret_cast<ushort4*>(out + (size_t)(c0 + oc) * R + r0 + orr) = o;
}

// ---------- bf16 MFMA GEMM: C[M][N] = A[M][K] @ Bt[N][K]^T + bias ----------
// m97 structure: linear LDS [rows][32], global_load_lds w16, 2 barriers/K-step.
// EPI 0: fp32 out ldc=N           (gemm_out)
// EPI 1: bf16 out ldc=N           (gemm_in -> xzb)
// EPI 2: fp32 TRANSPOSED out [N][8192]; bias b0|b1|b2 per 64-col; sigmoid col<64
// EPI 3: mix: bf16 out = (acc + b_si + D*xact) * sigmoid(gate)
template <int BM, int BN, int EPI>
__global__ __launch_bounds__(256)
void gemm_mfma(const u16* __restrict__ A, const u16* __restrict__ Bt,
               const float* __restrict__ b0, const float* __restrict__ b1,
               const float* __restrict__ b2,
               const u16* __restrict__ aux0, const u16* __restrict__ aux1,
               void* __restrict__ o0, int N, int K)
{
    constexpr int FM = BM / 32, FN = BN / 32;   // fragments per wave (wave tile BM/2 x BN/2)
    constexpr int CA = BM / 64, CB = BN / 64;   // 1KB staging chunks per wave
    __shared__ __align__(16) u16 As[BM][32];
    __shared__ __align__(16) u16 Bs[BN][32];

    const int tid  = threadIdx.x;
    const int lane = tid & 63;
    const int wid  = tid >> 6;
    const int wr   = (wid >> 1) * (BM / 2);
    const int wc   = (wid & 1)  * (BN / 2);
    const int row0 = blockIdx.y * BM;
    const int col0 = blockIdx.x * BN;

    const int lr = lane >> 2;        // staging row within 16-row chunk
    const int lc = (lane & 3) * 8;   // staging col (bf16 units; 16B chunks)
    const int fr = lane & 15;
    const int fq = lane >> 4;
    const int kb = fq * 8;

    f32x4 acc[FM][FN];
#pragma unroll
    for (int m = 0; m < FM; ++m)
#pragma unroll
        for (int n = 0; n < FN; ++n) acc[m][n] = (f32x4){0.f, 0.f, 0.f, 0.f};

    for (int k0 = 0; k0 < K; k0 += 32) {
#pragma unroll
        for (int i = 0; i < CA; ++i) {
            const int c = wid * CA + i;
            gll16(A + (size_t)(row0 + c * 16 + lr) * K + k0 + lc, &As[c * 16 + lr][lc]);
        }
#pragma unroll
        for (int i = 0; i < CB; ++i) {
            const int c = wid * CB + i;
            gll16(Bt + (size_t)(col0 + c * 16 + lr) * K + k0 + lc, &Bs[c * 16 + lr][lc]);
        }
        __syncthreads();   // drains vmcnt -> staged data visible
        bf16x8 af[FM], bg[FN];
#pragma unroll
        for (int m = 0; m < FM; ++m)
            af[m] = *reinterpret_cast<const bf16x8*>(&As[wr + m * 16 + fr][kb]);
#pragma unroll
        for (int n = 0; n < FN; ++n)
            bg[n] = *reinterpret_cast<const bf16x8*>(&Bs[wc + n * 16 + fr][kb]);
#pragma unroll
        for (int m = 0; m < FM; ++m)
#pragma unroll
            for (int n = 0; n < FN; ++n)
                acc[m][n] = __builtin_amdgcn_mfma_f32_16x16x32_bf16(af[m], bg[n], acc[m][n], 0, 0, 0);
        __syncthreads();   // all frag reads done before next-stage overwrite
    }

#pragma unroll
    for (int m = 0; m < FM; ++m) {
#pragma unroll
        for (int n = 0; n < FN; ++n) {
            const int gc  = col0 + wc + n * 16 + fr;
            const int gr0 = row0 + wr + m * 16 + fq * 4;
            if constexpr (EPI == 2) {
                float4 vv;
                float* vp = (float*)&vv;
#pragma unroll
                for (int j = 0; j < 4; ++j) {
                    float bb = (gc < 64) ? b0[gc] : (gc < 128) ? b1[gc - 64] : b2[gc - 128];
                    float v = acc[m][n][j] + bb;
                    if (gc < 64) v = sigmoid_f(v);
                    vp[j] = v;
                }
                *reinterpret_cast<float4*>(&((float*)o0)[(size_t)gc * 8192 + gr0]) = vv;
            } else {
#pragma unroll
                for (int j = 0; j < 4; ++j) {
                    const int gr = gr0 + j;
                    float v = acc[m][n][j];
                    if constexpr (EPI == 0) {
                        ((float*)o0)[(size_t)gr * N + gc] = v + b0[gc];
                    } else if constexpr (EPI == 1) {
                        ((u16*)o0)[(size_t)gr * N + gc] = f2bf(v + b0[gc]);
                    } else {  // EPI 3: mix
                        const size_t p = (size_t)gr * 2048 + gc;
                        float g  = bf2f(aux0[(size_t)gr * 4096 + gc]);   // gate
                        float xa = bf2f(aux1[p]);                        // xact
                        v = v + b0[gc] + b1[gc] * xa;
                        ((u16*)o0)[p] = f2bf(v * sigmoid_f(g));
                    }
                }
            }
        }
    }
    (void)b1; (void)b2; (void)aux0; (void)aux1;
}

// ---------- depthwise causal conv (K=3) + bias + SiLU, bf16 in/out ----------
__global__ __launch_bounds__(256)
void conv_silu(const u16* __restrict__ xz, const float* __restrict__ cw,
               const float* __restrict__ cb, u16* __restrict__ xact)
{
    const size_t g  = ((size_t)blockIdx.x * 256 + threadIdx.x) * 8;  // < 8192*2048
    const int    c0 = (int)(g & 2047);
    const size_t r  = g >> 11;
    const int    s  = (int)(r & (kSeq - 1));
    const u16* p = xz + r * 4096 + c0;
    u16 X0[8], X1[8] = {}, X2[8] = {};
    *reinterpret_cast<uint4*>(X0) = *reinterpret_cast<const uint4*>(p);
    if (s >= 1) *reinterpret_cast<uint4*>(X1) = *reinterpret_cast<const uint4*>(p - 4096);
    if (s >= 2) *reinterpret_cast<uint4*>(X2) = *reinterpret_cast<const uint4*>(p - 8192);
    u16 O[8];
#pragma unroll
    for (int j = 0; j < 8; ++j) {
        const int c = c0 + j;
        float v = bf2f(X2[j]) * cw[c * 3 + 0] + bf2f(X1[j]) * cw[c * 3 + 1]
                + bf2f(X0[j]) * cw[c * 3 + 2] + cb[c];
        O[j] = f2bf(v * sigmoid_f(v));
    }
    *reinterpret_cast<uint4*>(xact + r * 2048 + c0) = *reinterpret_cast<uint4*>(O);
}

// ---------- selective scan over transposed dtbcT [192][8192] ----------
__global__ __launch_bounds__(256)
void scan_kernel(const float* __restrict__ dtbcT, float* __restrict__ y)
{
    const int b = blockIdx.x >> 6;
    const int d = blockIdx.x & 63;
    const int t = threadIdx.x;
    const size_t col = (size_t)b * kSeq + t * 16;   // global row index base
    const float* dtp = dtbcT + (size_t)d         * 8192 + col;
    const float* Bp  = dtbcT + (size_t)(64 + d)  * 8192 + col;
    const float* Cp  = dtbcT + (size_t)(128 + d) * 8192 + col;

    float av[16], bv[16];
    float Acc = 1.f, Bcc = 0.f;
#pragma unroll
    for (int q = 0; q < 4; ++q) {
        float4 dv = *reinterpret_cast<const float4*>(dtp + q * 4);
        float4 Bv = *reinterpret_cast<const float4*>(Bp + q * 4);
        const float* dvp = (const float*)&dv;
        const float* bvp = (const float*)&Bv;
#pragma unroll
        for (int j = 0; j < 4; ++j) {
            const int i = q * 4 + j;
            float a  = 1.f - dvp[j];
            float bb = dvp[j] * bvp[j];
            av[i] = a; bv[i] = bb;
            Acc = a * Acc;
            Bcc = a * Bcc + bb;
        }
    }

    __shared__ float sA[256], sB[256];
    sA[t] = Acc; sB[t] = Bcc;
    __syncthreads();
    for (int off = 1; off < 256; off <<= 1) {
        float cA = sA[t], cB = sB[t];
        float pA = 1.f, pB = 0.f;
        if (t >= off) { pA = sA[t - off]; pB = sB[t - off]; }
        __syncthreads();
        if (t >= off) { sA[t] = cA * pA; sB[t] = cA * pB + cB; }
        __syncthreads();
    }

    float s = (t == 0) ? 0.f : sB[t - 1];
#pragma unroll
    for (int q = 0; q < 4; ++q) {
        float4 Cv = *reinterpret_cast<const float4*>(Cp + q * 4);
        const float* cvp = (const float*)&Cv;
#pragma unroll
        for (int j = 0; j < 4; ++j) {
            const int i = q * 4 + j;
            s = av[i] * s + bv[i];
            y[(col + i) * 64 + d] = cvp[j] * s;
        }
    }
}

// ---------- LayerNorm over 64 states -> bf16 ----------
__global__ __launch_bounds__(256)
void ln_kernel(const float* __restrict__ y, u16* __restrict__ ynb)
{
    const int w = threadIdx.x >> 6;
    const int l = threadIdx.x & 63;
    const size_t r = (size_t)blockIdx.x * 4 + w;
    float v  = y[r * 64 + l];
    float s  = v, s2 = v * v;
#pragma unroll
    for (int m = 1; m < 64; m <<= 1) {
        s  += __shfl_xor(s, m, 64);
        s2 += __shfl_xor(s2, m, 64);
    }
    float mu  = s * (1.f / 64.f);
    float var = s2 * (1.f / 64.f) - mu * mu;
    ynb[r * 64 + l] = f2bf((v - mu) * rsqrtf(var + 1e-5f));
}

}  // namespace

extern "C" void kernel_launch(void* const* d_in, const int* in_sizes, int n_in,
                              void* d_out, int out_size, void* d_ws, size_t ws_size,
                              hipStream_t stream)
{
    (void)in_sizes; (void)n_in; (void)out_size; (void)ws_size;
    const float* x     = (const float*)d_in[0];
    const float* W_in  = (const float*)d_in[1];
    const float* b_in  = (const float*)d_in[2];
    const float* cw    = (const float*)d_in[3];
    const float* cb    = (const float*)d_in[4];
    const float* W_dt  = (const float*)d_in[5];
    const float* b_dt  = (const float*)d_in[6];
    const float* W_B   = (const float*)d_in[7];
    const float* b_B   = (const float*)d_in[8];
    const float* W_C   = (const float*)d_in[9];
    const float* b_C   = (const float*)d_in[10];
    const float* W_si  = (const float*)d_in[11];
    const float* b_si  = (const float*)d_in[12];
    const float* Dv    = (const float*)d_in[13];
    const float* W_out = (const float*)d_in[14];
    const float* b_out = (const float*)d_in[15];
    float* out = (float*)d_out;

    char* ws = (char*)d_ws;
    u16*   xzb    = (u16*)  (ws);
    u16*   xb     = (u16*)  (ws + 67108864);
    u16*   xact   = (u16*)  (ws + 83886080);
    u16*   hb     = (u16*)  (ws + 117440512);
    float* dtbcT  = (float*)(ws + 150994944);
    float* ybuf   = (float*)(ws + 157286400);
    u16*   ynb    = (u16*)  (ws + 159383552);
    u16*   WinT   = (u16*)  (ws + 160432128);
    u16*   WoutT  = (u16*)  (ws + 168820736);
    u16*   WdtbcT = (u16*)  (ws + 173015040);
    u16*   WsiT   = (u16*)  (ws + 173801472);

    dim3 blk(256);

    // conversions / weight transposes
    convert_bf16<<<dim3((8192L * 1024 / 4 + 255) / 256), blk, 0, stream>>>(x, xb, 8192L * 1024 / 4);
    transpose_bf16<<<dim3(4096 / 32, 1024 / 32), blk, 0, stream>>>(W_in,  WinT,  1024, 4096);
    transpose_bf16<<<dim3(1024 / 32, 2048 / 32), blk, 0, stream>>>(W_out, WoutT, 2048, 1024);
    transpose_bf16<<<dim3(64 / 32, 2048 / 32), blk, 0, stream>>>(W_dt, WdtbcT,              2048, 64);
    transpose_bf16<<<dim3(64 / 32, 2048 / 32), blk, 0, stream>>>(W_B,  WdtbcT +  64 * 2048, 2048, 64);
    transpose_bf16<<<dim3(64 / 32, 2048 / 32), blk, 0, stream>>>(W_C,  WdtbcT + 128 * 2048, 2048, 64);
    transpose_bf16<<<dim3(2048 / 32, 64 / 32), blk, 0, stream>>>(W_si, WsiT, 64, 2048);

    // xzb = bf16(x @ W_in + b_in)   [8192][4096]
    gemm_mfma<128, 128, 1><<<dim3(4096 / 128, 8192 / 128), blk, 0, stream>>>(
        xb, WinT, b_in, nullptr, nullptr, nullptr, nullptr, xzb, 4096, 1024);
    // xact = silu(causal_conv(xzb[:, :2048]))
    conv_silu<<<dim3(8192L * 2048 / (8 * 256)), blk, 0, stream>>>(xzb, cw, cb, xact);
    // dtbcT[192][8192] = [sigmoid(xact@W_dt+b) | xact@W_B+b | xact@W_C+b]^T
    gemm_mfma<64, 64, 2><<<dim3(192 / 64, 8192 / 64), blk, 0, stream>>>(
        xact, WdtbcT, b_dt, b_B, b_C, nullptr, nullptr, dtbcT, 192, 2048);
    // y = selective_scan(dt, B, C)   [8192][64]
    scan_kernel<<<dim3(128), blk, 0, stream>>>(dtbcT, ybuf);
    // ynb = bf16(layernorm(y))
    ln_kernel<<<dim3(8192 / 4), blk, 0, stream>>>(ybuf, ynb);
    // hb = (ynb@W_si + b_si + D*xact) * sigmoid(gate)
    gemm_mfma<128, 128, 3><<<dim3(2048 / 128, 8192 / 128), blk, 0, stream>>>(
        ynb, WsiT, b_si, Dv, nullptr, xzb + 2048, xact, hb, 2048, 64);
    // out = hb @ W_out + b_out
    gemm_mfma<128, 128, 0><<<dim3(1024 / 128, 8192 / 128), blk, 0, stream>>>(
        hb, WoutT, b_out, nullptr, nullptr, nullptr, nullptr, out, 1024, 2048);
}

// Round 5
// 237.828 us; speedup vs baseline: 6.6000x; 1.1418x over previous
//
#include <hip/hip_runtime.h>
#include <hip/hip_bf16.h>
#include <math.h>

// SelectiveStateSpaceMixer — round 5: round-4 design with the K-subtile
// indexing fix (kk*32, not kk*16) in the fragment reads.
// BK=64 + both-sides XOR swizzle, bijective XCD block swizzle, merged prep.
// ws layout (bytes):
//   xzb    bf16[8192][4096]  67108864 @ 0
//   xb     bf16[8192][1024]  16777216 @ 67108864
//   xact   bf16[8192][2048]  33554432 @ 83886080
//   hb     bf16[8192][2048]  33554432 @ 117440512
//   dtbcT  f32 [192][8192]    6291456 @ 150994944
//   ybuf   f32 [8192][64]     2097152 @ 157286400
//   ynb    bf16[8192][64]     1048576 @ 159383552
//   WinT   bf16[4096][1024]   8388608 @ 160432128
//   WoutT  bf16[1024][2048]   4194304 @ 168820736
//   WdtbcT bf16[192][2048]     786432 @ 173015040
//   WsiT   bf16[2048][64]      262144 @ 173801472   end 174063616

namespace {

typedef __bf16 bf16x8 __attribute__((ext_vector_type(8)));
typedef float  f32x4  __attribute__((ext_vector_type(4)));
typedef unsigned short u16;

constexpr int kSeq = 4096;

__device__ __forceinline__ float sigmoid_f(float x) { return 1.0f / (1.0f + expf(-x)); }
__device__ __forceinline__ u16   f2bf(float f) { __bf16 h = (__bf16)f; return __builtin_bit_cast(u16, h); }
__device__ __forceinline__ float bf2f(u16 u)   { return (float)__builtin_bit_cast(__bf16, u); }

// async global->LDS, 16B per lane (dest = wave-uniform base + lane*16)
__device__ __forceinline__ void gll16(const u16* g, u16* l) {
    __builtin_amdgcn_global_load_lds(
        (const __attribute__((address_space(1))) unsigned int*)g,
        (__attribute__((address_space(3))) unsigned int*)l,
        16, 0, 0);
}

// bijective XCD-aware block swizzle (m204): contiguous tile chunk per XCD
__device__ __forceinline__ int xcd_swizzle(int lin, int nwg) {
    const int q = nwg >> 3, r = nwg & 7;
    const int xcd = lin & 7, idx = lin >> 3;
    return (xcd < r ? xcd * (q + 1) : r * (q + 1) + (xcd - r) * q) + idx;
}

// ---------- fp32 -> bf16 elementwise ----------
__global__ __launch_bounds__(256)
void convert_bf16(const float* __restrict__ in, u16* __restrict__ out, long n4)
{
    long i = (long)blockIdx.x * 256 + threadIdx.x;
    if (i >= n4) return;
    float4 v = reinterpret_cast<const float4*>(in)[i];
    ushort4 o = make_ushort4(f2bf(v.x), f2bf(v.y), f2bf(v.z), f2bf(v.w));
    reinterpret_cast<ushort4*>(out)[i] = o;
}

// ---------- 32x32 tile transpose body: fp32 [R][C] -> bf16 [C][R] ----------
__device__ __forceinline__ void tr_body(float (*tile)[33],
                                        const float* __restrict__ in, u16* __restrict__ out,
                                        int R, int C, int r0, int c0, int t)
{
    const int lr = t >> 3, lc = (t & 7) * 4;
    float4 v = *reinterpret_cast<const float4*>(in + (size_t)(r0 + lr) * C + c0 + lc);
    tile[lr][lc + 0] = v.x; tile[lr][lc + 1] = v.y;
    tile[lr][lc + 2] = v.z; tile[lr][lc + 3] = v.w;
    __syncthreads();
    const int oc = t >> 3, orr = (t & 7) * 4;
    ushort4 o = make_ushort4(f2bf(tile[orr + 0][oc]), f2bf(tile[orr + 1][oc]),
                             f2bf(tile[orr + 2][oc]), f2bf(tile[orr + 3][oc]));
    *reinterpret_cast<ushort4*>(out + (size_t)(c0 + oc) * R + r0 + orr) = o;
}

// grid (128,32,2): z=0 W_in [1024][4096]; z=1 W_out [2048][1024] (roles swapped)
__global__ __launch_bounds__(256)
void transpose_big(const float* __restrict__ Win, u16* __restrict__ WinT,
                   const float* __restrict__ Wout, u16* __restrict__ WoutT)
{
    __shared__ float tile[32][33];
    const int t = threadIdx.x;
    if (blockIdx.z == 0) {
        tr_body(tile, Win, WinT, 1024, 4096, blockIdx.y * 32, blockIdx.x * 32, t);
    } else {
        if (blockIdx.x >= 64) return;
        tr_body(tile, Wout, WoutT, 2048, 1024, blockIdx.x * 32, blockIdx.y * 32, t);
    }
}

// grid (2,64,4): z<3 -> W_dt/W_B/W_C [2048][64]; z=3 -> W_si [64][2048] (roles swapped)
__global__ __launch_bounds__(256)
void transpose_small(const float* __restrict__ Wdt, const float* __restrict__ WB,
                     const float* __restrict__ WC,  const float* __restrict__ Wsi,
                     u16* __restrict__ WdtbcT, u16* __restrict__ WsiT)
{
    __shared__ float tile[32][33];
    const int t = threadIdx.x;
    const int z = blockIdx.z;
    if (z < 3) {
        const float* in = (z == 0) ? Wdt : (z == 1) ? WB : WC;
        u16* out = WdtbcT + (size_t)z * 64 * 2048;
        tr_body(tile, in, out, 2048, 64, blockIdx.y * 32, blockIdx.x * 32, t);
    } else {
        tr_body(tile, Wsi, WsiT, 64, 2048, blockIdx.x * 32, blockIdx.y * 32, t);
    }
}

// ---------- bf16 MFMA GEMM: C[M][N] = A[M][K] @ Bt[N][K]^T + bias ----------
// 2-barrier structure, BK=64, linear-LDS global_load_lds w16 with both-sides
// XOR swizzle (16B-slot j of row r holds global slot j^(r&7)) -> 2-way reads.
// EPI 0: fp32 out ldc=N           (gemm_out)
// EPI 1: bf16 out ldc=N           (gemm_in -> xzb)
// EPI 2: fp32 TRANSPOSED out [N][8192]; bias b0|b1|b2 per 64-col; sigmoid col<64
// EPI 3: mix: bf16 out = (acc + b_si + D*xact) * sigmoid(gate)
template <int BM, int BN, int EPI>
__global__ __launch_bounds__(256)
void gemm_mfma(const u16* __restrict__ A, const u16* __restrict__ Bt,
               const float* __restrict__ b0, const float* __restrict__ b1,
               const float* __restrict__ b2,
               const u16* __restrict__ aux0, const u16* __restrict__ aux1,
               void* __restrict__ o0, int N, int K, int nbx)
{
    constexpr int FM = BM / 32, FN = BN / 32;   // fragments per wave (wave tile BM/2 x BN/2)
    constexpr int CA = BM / 32, CB = BN / 32;   // 1KB (8-row) staging chunks per wave
    __shared__ __align__(16) u16 As[BM][64];
    __shared__ __align__(16) u16 Bs[BN][64];

    const int tid  = threadIdx.x;
    const int lane = tid & 63;
    const int wid  = tid >> 6;
    const int wr   = (wid >> 1) * (BM / 2);
    const int wc   = (wid & 1)  * (BN / 2);
    const int swz  = xcd_swizzle(blockIdx.x, gridDim.x);
    const int row0 = (swz / nbx) * BM;
    const int col0 = (swz % nbx) * BN;

    const int srow = lane >> 3;                      // row within 8-row chunk
    const int scol = ((lane & 7) ^ srow) * 8;        // pre-swizzled global col (elems)
    const int fr   = lane & 15;
    const int fq   = lane >> 4;

    f32x4 acc[FM][FN];
#pragma unroll
    for (int m = 0; m < FM; ++m)
#pragma unroll
        for (int n = 0; n < FN; ++n) acc[m][n] = (f32x4){0.f, 0.f, 0.f, 0.f};

    for (int k0 = 0; k0 < K; k0 += 64) {
#pragma unroll
        for (int i = 0; i < CA; ++i) {
            const int c = wid * CA + i;
            gll16(A + (size_t)(row0 + c * 8 + srow) * K + k0 + scol,
                  &As[0][0] + c * 512 + lane * 8);
        }
#pragma unroll
        for (int i = 0; i < CB; ++i) {
            const int c = wid * CB + i;
            gll16(Bt + (size_t)(col0 + c * 8 + srow) * K + k0 + scol,
                  &Bs[0][0] + c * 512 + lane * 8);
        }
        __syncthreads();   // drains vmcnt -> staged data visible
#pragma unroll
        for (int kk = 0; kk < 2; ++kk) {
            bf16x8 af[FM], bg[FN];
#pragma unroll
            for (int m = 0; m < FM; ++m) {
                const int rr = wr + m * 16 + fr;
                af[m] = *reinterpret_cast<const bf16x8*>(
                    &As[rr][(kk * 32 + fq * 8) ^ ((rr & 7) * 8)]);
            }
#pragma unroll
            for (int n = 0; n < FN; ++n) {
                const int rr = wc + n * 16 + fr;
                bg[n] = *reinterpret_cast<const bf16x8*>(
                    &Bs[rr][(kk * 32 + fq * 8) ^ ((rr & 7) * 8)]);
            }
#pragma unroll
            for (int m = 0; m < FM; ++m)
#pragma unroll
                for (int n = 0; n < FN; ++n)
                    acc[m][n] = __builtin_amdgcn_mfma_f32_16x16x32_bf16(af[m], bg[n], acc[m][n], 0, 0, 0);
        }
        __syncthreads();   // all frag reads done before next-stage overwrite
    }

#pragma unroll
    for (int m = 0; m < FM; ++m) {
#pragma unroll
        for (int n = 0; n < FN; ++n) {
            const int gc  = col0 + wc + n * 16 + fr;
            const int gr0 = row0 + wr + m * 16 + fq * 4;
            if constexpr (EPI == 2) {
                float4 vv;
                float* vp = (float*)&vv;
#pragma unroll
                for (int j = 0; j < 4; ++j) {
                    float bb = (gc < 64) ? b0[gc] : (gc < 128) ? b1[gc - 64] : b2[gc - 128];
                    float v = acc[m][n][j] + bb;
                    if (gc < 64) v = sigmoid_f(v);
                    vp[j] = v;
                }
                *reinterpret_cast<float4*>(&((float*)o0)[(size_t)gc * 8192 + gr0]) = vv;
            } else {
#pragma unroll
                for (int j = 0; j < 4; ++j) {
                    const int gr = gr0 + j;
                    float v = acc[m][n][j];
                    if constexpr (EPI == 0) {
                        ((float*)o0)[(size_t)gr * N + gc] = v + b0[gc];
                    } else if constexpr (EPI == 1) {
                        ((u16*)o0)[(size_t)gr * N + gc] = f2bf(v + b0[gc]);
                    } else {  // EPI 3: mix
                        const size_t p = (size_t)gr * 2048 + gc;
                        float g  = bf2f(aux0[(size_t)gr * 4096 + gc]);   // gate
                        float xa = bf2f(aux1[p]);                        // xact
                        v = v + b0[gc] + b1[gc] * xa;
                        ((u16*)o0)[p] = f2bf(v * sigmoid_f(g));
                    }
                }
            }
        }
    }
    (void)b1; (void)b2; (void)aux0; (void)aux1;
}

// ---------- depthwise causal conv (K=3) + bias + SiLU, bf16 in/out ----------
__global__ __launch_bounds__(256)
void conv_silu(const u16* __restrict__ xz, const float* __restrict__ cw,
               const float* __restrict__ cb, u16* __restrict__ xact)
{
    const size_t g  = ((size_t)blockIdx.x * 256 + threadIdx.x) * 8;  // < 8192*2048
    const int    c0 = (int)(g & 2047);
    const size_t r  = g >> 11;
    const int    s  = (int)(r & (kSeq - 1));
    const u16* p = xz + r * 4096 + c0;
    u16 X0[8], X1[8] = {}, X2[8] = {};
    *reinterpret_cast<uint4*>(X0) = *reinterpret_cast<const uint4*>(p);
    if (s >= 1) *reinterpret_cast<uint4*>(X1) = *reinterpret_cast<const uint4*>(p - 4096);
    if (s >= 2) *reinterpret_cast<uint4*>(X2) = *reinterpret_cast<const uint4*>(p - 8192);
    u16 O[8];
#pragma unroll
    for (int j = 0; j < 8; ++j) {
        const int c = c0 + j;
        float v = bf2f(X2[j]) * cw[c * 3 + 0] + bf2f(X1[j]) * cw[c * 3 + 1]
                + bf2f(X0[j]) * cw[c * 3 + 2] + cb[c];
        O[j] = f2bf(v * sigmoid_f(v));
    }
    *reinterpret_cast<uint4*>(xact + r * 2048 + c0) = *reinterpret_cast<uint4*>(O);
}

// ---------- selective scan over transposed dtbcT [192][8192] ----------
__global__ __launch_bounds__(256)
void scan_kernel(const float* __restrict__ dtbcT, float* __restrict__ y)
{
    const int b = blockIdx.x >> 6;
    const int d = blockIdx.x & 63;
    const int t = threadIdx.x;
    const size_t col = (size_t)b * kSeq + t * 16;
    const float* dtp = dtbcT + (size_t)d         * 8192 + col;
    const float* Bp  = dtbcT + (size_t)(64 + d)  * 8192 + col;
    const float* Cp  = dtbcT + (size_t)(128 + d) * 8192 + col;

    float av[16], bv[16];
    float Acc = 1.f, Bcc = 0.f;
#pragma unroll
    for (int q = 0; q < 4; ++q) {
        float4 dv = *reinterpret_cast<const float4*>(dtp + q * 4);
        float4 Bv = *reinterpret_cast<const float4*>(Bp + q * 4);
        const float* dvp = (const float*)&dv;
        const float* bvp = (const float*)&Bv;
#pragma unroll
        for (int j = 0; j < 4; ++j) {
            const int i = q * 4 + j;
            float a  = 1.f - dvp[j];
            float bb = dvp[j] * bvp[j];
            av[i] = a; bv[i] = bb;
            Acc = a * Acc;
            Bcc = a * Bcc + bb;
        }
    }

    __shared__ float sA[256], sB[256];
    sA[t] = Acc; sB[t] = Bcc;
    __syncthreads();
    for (int off = 1; off < 256; off <<= 1) {
        float cA = sA[t], cB = sB[t];
        float pA = 1.f, pB = 0.f;
        if (t >= off) { pA = sA[t - off]; pB = sB[t - off]; }
        __syncthreads();
        if (t >= off) { sA[t] = cA * pA; sB[t] = cA * pB + cB; }
        __syncthreads();
    }

    float s = (t == 0) ? 0.f : sB[t - 1];
#pragma unroll
    for (int q = 0; q < 4; ++q) {
        float4 Cv = *reinterpret_cast<const float4*>(Cp + q * 4);
        const float* cvp = (const float*)&Cv;
#pragma unroll
        for (int j = 0; j < 4; ++j) {
            const int i = q * 4 + j;
            s = av[i] * s + bv[i];
            y[(col + i) * 64 + d] = cvp[j] * s;
        }
    }
}

// ---------- LayerNorm over 64 states -> bf16 ----------
__global__ __launch_bounds__(256)
void ln_kernel(const float* __restrict__ y, u16* __restrict__ ynb)
{
    const int w = threadIdx.x >> 6;
    const int l = threadIdx.x & 63;
    const size_t r = (size_t)blockIdx.x * 4 + w;
    float v  = y[r * 64 + l];
    float s  = v, s2 = v * v;
#pragma unroll
    for (int m = 1; m < 64; m <<= 1) {
        s  += __shfl_xor(s, m, 64);
        s2 += __shfl_xor(s2, m, 64);
    }
    float mu  = s * (1.f / 64.f);
    float var = s2 * (1.f / 64.f) - mu * mu;
    ynb[r * 64 + l] = f2bf((v - mu) * rsqrtf(var + 1e-5f));
}

}  // namespace

extern "C" void kernel_launch(void* const* d_in, const int* in_sizes, int n_in,
                              void* d_out, int out_size, void* d_ws, size_t ws_size,
                              hipStream_t stream)
{
    (void)in_sizes; (void)n_in; (void)out_size; (void)ws_size;
    const float* x     = (const float*)d_in[0];
    const float* W_in  = (const float*)d_in[1];
    const float* b_in  = (const float*)d_in[2];
    const float* cw    = (const float*)d_in[3];
    const float* cb    = (const float*)d_in[4];
    const float* W_dt  = (const float*)d_in[5];
    const float* b_dt  = (const float*)d_in[6];
    const float* W_B   = (const float*)d_in[7];
    const float* b_B   = (const float*)d_in[8];
    const float* W_C   = (const float*)d_in[9];
    const float* b_C   = (const float*)d_in[10];
    const float* W_si  = (const float*)d_in[11];
    const float* b_si  = (const float*)d_in[12];
    const float* Dv    = (const float*)d_in[13];
    const float* W_out = (const float*)d_in[14];
    const float* b_out = (const float*)d_in[15];
    float* out = (float*)d_out;

    char* ws = (char*)d_ws;
    u16*   xzb    = (u16*)  (ws);
    u16*   xb     = (u16*)  (ws + 67108864);
    u16*   xact   = (u16*)  (ws + 83886080);
    u16*   hb     = (u16*)  (ws + 117440512);
    float* dtbcT  = (float*)(ws + 150994944);
    float* ybuf   = (float*)(ws + 157286400);
    u16*   ynb    = (u16*)  (ws + 159383552);
    u16*   WinT   = (u16*)  (ws + 160432128);
    u16*   WoutT  = (u16*)  (ws + 168820736);
    u16*   WdtbcT = (u16*)  (ws + 173015040);
    u16*   WsiT   = (u16*)  (ws + 173801472);

    dim3 blk(256);

    // prep: x->bf16, all weight transposes (3 launches)
    convert_bf16<<<dim3((8192L * 1024 / 4 + 255) / 256), blk, 0, stream>>>(x, xb, 8192L * 1024 / 4);
    transpose_big<<<dim3(128, 32, 2), blk, 0, stream>>>(W_in, WinT, W_out, WoutT);
    transpose_small<<<dim3(2, 64, 4), blk, 0, stream>>>(W_dt, W_B, W_C, W_si, WdtbcT, WsiT);

    // xzb = bf16(x @ W_in + b_in)   [8192][4096]
    gemm_mfma<128, 128, 1><<<dim3(32 * 64), blk, 0, stream>>>(
        xb, WinT, b_in, nullptr, nullptr, nullptr, nullptr, xzb, 4096, 1024, 32);
    // xact = silu(causal_conv(xzb[:, :2048]))
    conv_silu<<<dim3(8192L * 2048 / (8 * 256)), blk, 0, stream>>>(xzb, cw, cb, xact);
    // dtbcT[192][8192] = [sigmoid(xact@W_dt+b) | xact@W_B+b | xact@W_C+b]^T
    gemm_mfma<64, 64, 2><<<dim3(3 * 128), blk, 0, stream>>>(
        xact, WdtbcT, b_dt, b_B, b_C, nullptr, nullptr, dtbcT, 192, 2048, 3);
    // y = selective_scan(dt, B, C)   [8192][64]
    scan_kernel<<<dim3(128), blk, 0, stream>>>(dtbcT, ybuf);
    // ynb = bf16(layernorm(y))
    ln_kernel<<<dim3(8192 / 4), blk, 0, stream>>>(ybuf, ynb);
    // hb = (ynb@W_si + b_si + D*xact) * sigmoid(gate)
    gemm_mfma<128, 128, 3><<<dim3(16 * 64), blk, 0, stream>>>(
        ynb, WsiT, b_si, Dv, nullptr, xzb + 2048, xact, hb, 2048, 64, 16);
    // out = hb @ W_out + b_out
    gemm_mfma<128, 128, 0><<<dim3(8 * 64), blk, 0, stream>>>(
        hb, WoutT, b_out, nullptr, nullptr, nullptr, nullptr, out, 1024, 2048, 8);
}